// Round 1
// baseline (321.263 us; speedup 1.0000x reference)
//
#include <hip/hip_runtime.h>

typedef __attribute__((ext_vector_type(8))) short short8;
typedef __attribute__((ext_vector_type(8))) unsigned short ushort8;
typedef __attribute__((ext_vector_type(4))) float f32x4;
typedef unsigned short ushort_t;

__device__ __forceinline__ ushort_t f2bf(float f) {
    unsigned u = __builtin_bit_cast(unsigned, f);
    u += 0x7fffu + ((u >> 16) & 1u);
    return (ushort_t)(u >> 16);
}

__device__ __forceinline__ void load_lds16(const void* gp, void* lp) {
    __builtin_amdgcn_global_load_lds(
        (const __attribute__((address_space(1))) void*)gp,
        (__attribute__((address_space(3))) void*)lp, 16, 0, 0);
}

// ---------------------------------------------------------------------------
// Weight conversion: 5 f32 arrays -> bf16, one launch.
// ---------------------------------------------------------------------------
__global__ __launch_bounds__(256) void cvt5_kernel(
    const float* __restrict__ s0, const float* __restrict__ s1,
    const float* __restrict__ s2, const float* __restrict__ s3,
    const float* __restrict__ s4,
    ushort_t* __restrict__ d0, ushort_t* __restrict__ d1,
    ushort_t* __restrict__ d2, ushort_t* __restrict__ d3,
    ushort_t* __restrict__ d4,
    int n0, int n1, int n2, int n3, int n4) {
    long c0 = n0 >> 3, c1 = c0 + (n1 >> 3), c2 = c1 + (n2 >> 3);
    long c3 = c2 + (n3 >> 3), c4 = c3 + (n4 >> 3);
    for (long c = (long)blockIdx.x * blockDim.x + threadIdx.x; c < c4;
         c += (long)gridDim.x * blockDim.x) {
        const float* s; ushort_t* d; long i;
        if (c < c0)      { s = s0; d = d0; i = c; }
        else if (c < c1) { s = s1; d = d1; i = c - c0; }
        else if (c < c2) { s = s2; d = d2; i = c - c1; }
        else if (c < c3) { s = s3; d = d3; i = c - c2; }
        else             { s = s4; d = d4; i = c - c3; }
        i <<= 3;
        f32x4 a = *(const f32x4*)(s + i);
        f32x4 b = *(const f32x4*)(s + i + 4);
        ushort8 o;
        o[0] = f2bf(a[0]); o[1] = f2bf(a[1]); o[2] = f2bf(a[2]); o[3] = f2bf(a[3]);
        o[4] = f2bf(b[0]); o[5] = f2bf(b[1]); o[6] = f2bf(b[2]); o[7] = f2bf(b[3]);
        *(ushort8*)(d + i) = o;
    }
}

// ---------------------------------------------------------------------------
// Average-patch pooling: conv(stride16,k16)+mean over positions == conv_w
// applied to the mean 16x16 patch. ap[bt][c*256+i*16+j] (bf16).
// Grid: 160*48 blocks (bt, c, i); 256 threads.
// ---------------------------------------------------------------------------
__global__ __launch_bounds__(256) void pool_kernel(const float* __restrict__ x,
                                                   ushort_t* __restrict__ ap) {
    int gid = blockIdx.x;
    int bt = gid / 48, rc = gid % 48;
    int c = rc >> 4, i = rc & 15;
    int b = bt / 20, t = bt % 20;
    const float* base = x + (size_t)((b * 3 + c) * 20 + t) * 50176;
    int tid = threadIdx.x;
    int s = tid & 3;
    f32x4 acc = {0.f, 0.f, 0.f, 0.f};
    #pragma unroll
    for (int it = 0; it < 4; ++it) {
        int task = (tid >> 2) + (it << 6);
        if (task < 196) {
            int pi = task / 14, w4g = task % 14;
            const float* p = base + (16 * pi + i) * 224 + (w4g * 16 + s * 4);
            acc += *(const f32x4*)p;
        }
    }
    __shared__ __align__(16) f32x4 red[256];
    red[tid] = acc;
    __syncthreads();
    for (int str = 128; str >= 4; str >>= 1) {
        if (tid < str) red[tid] += red[tid + str];
        __syncthreads();
    }
    __shared__ float fin[16];
    if (tid < 4) {
        f32x4 v = red[tid];
        fin[tid * 4 + 0] = v[0]; fin[tid * 4 + 1] = v[1];
        fin[tid * 4 + 2] = v[2]; fin[tid * 4 + 3] = v[3];
    }
    __syncthreads();
    if (tid < 16) {
        float val = fin[tid] * (1.0f / 196.0f);
        ap[(size_t)bt * 768 + c * 256 + i * 16 + tid] = f2bf(val);
    }
}

// ---------------------------------------------------------------------------
// bf16 MFMA GEMM: C[M,N] = A[M,K] @ B[N,K]^T (+bias) (+res) ; 64x64 tile,
// single-wave WG, double-buffered LDS via global_load_lds with XOR-swizzled
// source (rule 21) so ds_read_b128 is conflict-free.
// ---------------------------------------------------------------------------
template <bool OUT_BF16, bool HAS_BIAS, bool HAS_RES, bool CLS_SWAP>
__global__ __launch_bounds__(64) void gemm_kernel(
    const ushort_t* __restrict__ A, const ushort_t* __restrict__ B,
    void* __restrict__ Cv, const float* __restrict__ bias,
    const float* __restrict__ res, int M, int N, int K) {
    __shared__ __align__(16) char lds[32768];
    const int lane = threadIdx.x;
    const int tn = blockIdx.x, tm = blockIdx.y;

    f32x4 acc[4][4];
    #pragma unroll
    for (int m = 0; m < 4; ++m)
        #pragma unroll
        for (int n = 0; n < 4; ++n)
            acc[m][n] = (f32x4){0.f, 0.f, 0.f, 0.f};

    const int nK = K >> 6;
    const int rbase = lane >> 3, cc = lane & 7;

    auto stage = [&](int k0, int buf) {
        char* lA = lds + buf * 16384;
        char* lB = lA + 8192;
        #pragma unroll
        for (int j = 0; j < 8; ++j) {
            int row = j * 8 + rbase;
            int cf = cc ^ (row & 7);
            int ga = tm * 64 + row; if (ga > M - 1) ga = M - 1;
            load_lds16(A + (size_t)ga * K + (k0 + cf * 8), lA + j * 1024);
            load_lds16(B + (size_t)(tn * 64 + row) * K + (k0 + cf * 8), lB + j * 1024);
        }
    };

    stage(0, 0);
    for (int t = 0; t < nK; ++t) {
        int cur = t & 1;
        asm volatile("s_waitcnt lgkmcnt(0)" ::: "memory");
        if (t + 1 < nK) {
            stage((t + 1) << 6, cur ^ 1);
            asm volatile("s_waitcnt vmcnt(16)" ::: "memory");
        } else {
            asm volatile("s_waitcnt vmcnt(0)" ::: "memory");
        }
        __builtin_amdgcn_sched_barrier(0);
        const char* lA = lds + cur * 16384;
        const char* lB = lA + 8192;
        #pragma unroll
        for (int ks = 0; ks < 2; ++ks) {
            short8 av[4], bv[4];
            const int rlo = lane & 15;
            const int chi = ks * 4 + (lane >> 4);
            #pragma unroll
            for (int m = 0; m < 4; ++m) {
                int r = m * 16 + rlo;
                av[m] = *(const short8*)(lA + r * 128 + ((chi ^ (r & 7)) << 4));
            }
            #pragma unroll
            for (int n = 0; n < 4; ++n) {
                int r = n * 16 + rlo;
                bv[n] = *(const short8*)(lB + r * 128 + ((chi ^ (r & 7)) << 4));
            }
            #pragma unroll
            for (int m = 0; m < 4; ++m)
                #pragma unroll
                for (int n = 0; n < 4; ++n)
                    acc[m][n] = __builtin_amdgcn_mfma_f32_16x16x32_bf16(
                        av[m], bv[n], acc[m][n], 0, 0, 0);
        }
    }

    const int c_l = lane & 15, r_q = (lane >> 4) * 4;
    #pragma unroll
    for (int m = 0; m < 4; ++m) {
        #pragma unroll
        for (int reg = 0; reg < 4; ++reg) {
            int r_ = tm * 64 + m * 16 + r_q + reg;
            if (r_ < M) {
                int r2 = r_;
                if (CLS_SWAP) {
                    int bb = r_ / 25, rem = r_ % 25;
                    if (rem % 5 == 0) r2 = bb * 25 + ((rem / 5 + 1) % 5) * 5;
                }
                #pragma unroll
                for (int n = 0; n < 4; ++n) {
                    int cc_ = tn * 64 + n * 16 + c_l;
                    float v = acc[m][n][reg];
                    if (HAS_BIAS) v += bias[cc_];
                    if (HAS_RES) v += res[(size_t)r_ * N + cc_];
                    if (OUT_BF16) ((ushort_t*)Cv)[(size_t)r2 * N + cc_] = f2bf(v);
                    else          ((float*)Cv)[(size_t)r2 * N + cc_] = v;
                }
            }
        }
    }
}

// ---------------------------------------------------------------------------
// Build initial g (B,5,5,D): cls tokens + xt = xr + time_embed + te
// ---------------------------------------------------------------------------
__global__ __launch_bounds__(256) void build_g_kernel(
    const float* __restrict__ xr, const float* __restrict__ temb,
    const float* __restrict__ ts, const float* __restrict__ w_num,
    const float* __restrict__ b_num, const float* __restrict__ cls,
    float* __restrict__ g) {
    int r = blockIdx.x, tid = threadIdx.x;
    int b = r / 25, rem = r % 25, n = rem / 5, k = rem % 5;
    #pragma unroll
    for (int j = 0; j < 6; ++j) {
        int d = tid + j * 256;
        float val;
        if (k == 0) {
            val = cls[n * 1536 + d];
        } else {
            int t = n * 4 + k - 1;
            val = xr[(size_t)(b * 20 + t) * 1536 + d] + temb[t * 1536 + d] +
                  ts[b] * w_num[d] + b_num[d];
        }
        g[(size_t)r * 1536 + d] = val;
    }
}

// ---------------------------------------------------------------------------
// LayerNorm over D=1536 -> bf16
// ---------------------------------------------------------------------------
__global__ __launch_bounds__(256) void ln_kernel(
    const float* __restrict__ g, const float* __restrict__ gamma,
    const float* __restrict__ beta, ushort_t* __restrict__ hn) {
    int r = blockIdx.x, tid = threadIdx.x;
    const float* x = g + (size_t)r * 1536;
    float v[6], s = 0.f, s2 = 0.f;
    #pragma unroll
    for (int j = 0; j < 6; ++j) {
        v[j] = x[tid + j * 256];
        s += v[j]; s2 += v[j] * v[j];
    }
    #pragma unroll
    for (int m = 1; m < 64; m <<= 1) { s += __shfl_xor(s, m); s2 += __shfl_xor(s2, m); }
    __shared__ float red[8];
    int wid = tid >> 6;
    if ((tid & 63) == 0) { red[wid] = s; red[4 + wid] = s2; }
    __syncthreads();
    s  = red[0] + red[1] + red[2] + red[3];
    s2 = red[4] + red[5] + red[6] + red[7];
    float mean = s * (1.0f / 1536.0f);
    float var  = s2 * (1.0f / 1536.0f) - mean * mean;
    float rstd = rsqrtf(var + 1e-5f);
    #pragma unroll
    for (int j = 0; j < 6; ++j) {
        int d = tid + j * 256;
        float y = (v[j] - mean) * rstd * gamma[d] + beta[d];
        hn[(size_t)r * 1536 + d] = f2bf(y);
    }
}

// ---------------------------------------------------------------------------
// Attention: one wave per (group, head). 5 tokens, hd=128 (2 dims/lane).
// ---------------------------------------------------------------------------
__global__ __launch_bounds__(64) void attn_kernel(const float* __restrict__ qkv,
                                                  ushort_t* __restrict__ o) {
    int gid = blockIdx.x;
    int h = gid % 12, gg = gid / 12;
    int l = threadIdx.x;
    const float* basep = qkv + (size_t)gg * 5 * 4608 + h * 128 + 2 * l;
    float q[5][2], k[5][2], v[5][2];
    #pragma unroll
    for (int tt = 0; tt < 5; ++tt) {
        float2 qv = *(const float2*)(basep + tt * 4608);
        float2 kv = *(const float2*)(basep + tt * 4608 + 1536);
        float2 vv = *(const float2*)(basep + tt * 4608 + 3072);
        q[tt][0] = qv.x; q[tt][1] = qv.y;
        k[tt][0] = kv.x; k[tt][1] = kv.y;
        v[tt][0] = vv.x; v[tt][1] = vv.y;
    }
    float sc[5][5];
    #pragma unroll
    for (int i = 0; i < 5; ++i)
        #pragma unroll
        for (int j = 0; j < 5; ++j)
            sc[i][j] = q[i][0] * k[j][0] + q[i][1] * k[j][1];
    #pragma unroll
    for (int m = 1; m < 64; m <<= 1)
        #pragma unroll
        for (int i = 0; i < 5; ++i)
            #pragma unroll
            for (int j = 0; j < 5; ++j)
                sc[i][j] += __shfl_xor(sc[i][j], m);
    const float scale = 0.08838834764831845f;
    float a_[5][5];
    #pragma unroll
    for (int i = 0; i < 5; ++i) {
        float mx = -1e30f;
        #pragma unroll
        for (int j = 0; j < 5; ++j) mx = fmaxf(mx, sc[i][j]);
        float sum = 0.f;
        #pragma unroll
        for (int j = 0; j < 5; ++j) { a_[i][j] = __expf((sc[i][j] - mx) * scale); sum += a_[i][j]; }
        float inv = 1.0f / sum;
        #pragma unroll
        for (int j = 0; j < 5; ++j) a_[i][j] *= inv;
    }
    #pragma unroll
    for (int i = 0; i < 5; ++i) {
        float o0 = 0.f, o1 = 0.f;
        #pragma unroll
        for (int j = 0; j < 5; ++j) { o0 += a_[i][j] * v[j][0]; o1 += a_[i][j] * v[j][1]; }
        ushort2 w; w.x = f2bf(o0); w.y = f2bf(o1);
        *(ushort2*)(o + (size_t)(gg * 5 + i) * 1536 + h * 128 + 2 * l) = w;
    }
}

// ---------------------------------------------------------------------------
// Head: out[b,c] = (g[b,4,4,:] + xr[b,19,:]) . w_head[c,:] + b_head[c]
// ---------------------------------------------------------------------------
__global__ __launch_bounds__(64) void head_kernel(
    const float* __restrict__ gfin, const float* __restrict__ xr,
    const float* __restrict__ w_head, const float* __restrict__ b_head,
    float* __restrict__ out) {
    int b = blockIdx.x, l = threadIdx.x;
    const float* gv = gfin + (size_t)(b * 25 + 24) * 1536;
    const float* xv = xr + (size_t)(b * 20 + 19) * 1536;
    float acc[7] = {0, 0, 0, 0, 0, 0, 0};
    for (int d = l; d < 1536; d += 64) {
        float xval = gv[d] + xv[d];
        #pragma unroll
        for (int c = 0; c < 7; ++c) acc[c] += xval * w_head[c * 1536 + d];
    }
    #pragma unroll
    for (int c = 0; c < 7; ++c)
        #pragma unroll
        for (int m = 1; m < 64; m <<= 1) acc[c] += __shfl_xor(acc[c], m);
    if (l == 0) {
        #pragma unroll
        for (int c = 0; c < 7; ++c) out[b * 7 + c] = acc[c] + b_head[c];
    }
}

// ---------------------------------------------------------------------------
// Workspace layout (bytes)
// ---------------------------------------------------------------------------
#define OFF_WQ   0u
#define OFF_WT   14155776u
#define OFF_WF   18874368u
#define OFF_WR   23592960u
#define OFF_WC   28311552u
#define OFF_AP   30670848u
#define OFF_FBF  30916608u
#define OFF_XR   31408128u
#define OFF_GA   32391168u
#define OFF_GB   33619968u
#define OFF_HN   34848768u
#define OFF_QKV  35463168u
#define OFF_OBF  39149568u
#define OFF_T1   39763968u

extern "C" void kernel_launch(void* const* d_in, const int* in_sizes, int n_in,
                              void* d_out, int out_size, void* d_ws, size_t ws_size,
                              hipStream_t stream) {
    const float* x      = (const float*)d_in[0];
    const float* ts     = (const float*)d_in[1];
    const float* conv_w = (const float*)d_in[2];
    const float* conv_b = (const float*)d_in[3];
    const float* w_red  = (const float*)d_in[4];
    const float* b_red  = (const float*)d_in[5];
    const float* w_num  = (const float*)d_in[6];
    const float* b_num  = (const float*)d_in[7];
    const float* temb   = (const float*)d_in[8];
    const float* cls    = (const float*)d_in[9];
    const float* ln_g   = (const float*)d_in[10];
    const float* ln_b   = (const float*)d_in[11];
    const float* w_qkv  = (const float*)d_in[12];
    const float* w_tp   = (const float*)d_in[13];
    const float* b_tp   = (const float*)d_in[14];
    const float* w_tf   = (const float*)d_in[15];
    const float* b_tf   = (const float*)d_in[16];
    const float* w_head = (const float*)d_in[17];
    const float* b_head = (const float*)d_in[18];

    char* ws = (char*)d_ws;
    ushort_t* WQ  = (ushort_t*)(ws + OFF_WQ);
    ushort_t* WT  = (ushort_t*)(ws + OFF_WT);
    ushort_t* WF  = (ushort_t*)(ws + OFF_WF);
    ushort_t* WR  = (ushort_t*)(ws + OFF_WR);
    ushort_t* WC  = (ushort_t*)(ws + OFF_WC);
    ushort_t* AP  = (ushort_t*)(ws + OFF_AP);
    ushort_t* FBF = (ushort_t*)(ws + OFF_FBF);
    float*    XR  = (float*)(ws + OFF_XR);
    float*    GA  = (float*)(ws + OFF_GA);
    float*    GB  = (float*)(ws + OFF_GB);
    ushort_t* HN  = (ushort_t*)(ws + OFF_HN);
    float*    QKV = (float*)(ws + OFF_QKV);
    ushort_t* OBF = (ushort_t*)(ws + OFF_OBF);
    ushort_t* T1  = (ushort_t*)(ws + OFF_T1);

    // 1) weights -> bf16
    cvt5_kernel<<<1024, 256, 0, stream>>>(w_qkv, w_tp, w_tf, w_red, conv_w,
                                          WQ, WT, WF, WR, WC,
                                          7077888, 2359296, 2359296, 2359296, 1179648);
    // 2) average-patch pooling
    pool_kernel<<<7680, 256, 0, stream>>>(x, AP);
    // 3) f = ap @ conv_w^T + conv_b   (bf16 out)
    gemm_kernel<true, true, false, false><<<dim3(24, 3), 64, 0, stream>>>(
        AP, WC, FBF, conv_b, nullptr, 160, 1536, 768);
    // 4) xr = f @ w_red^T + b_red     (f32 out)
    gemm_kernel<false, true, false, false><<<dim3(24, 3), 64, 0, stream>>>(
        FBF, WR, XR, b_red, nullptr, 160, 1536, 1536);
    // 5) build g
    build_g_kernel<<<200, 256, 0, stream>>>(XR, temb, ts, w_num, b_num, cls, GA);

    float* gsrc = GA;
    float* gdst = GB;
    for (int it = 0; it < 4; ++it) {
        ln_kernel<<<200, 256, 0, stream>>>(gsrc, ln_g, ln_b, HN);
        gemm_kernel<false, false, false, false><<<dim3(72, 4), 64, 0, stream>>>(
            HN, WQ, QKV, nullptr, nullptr, 200, 4608, 1536);
        attn_kernel<<<480, 64, 0, stream>>>(QKV, OBF);
        gemm_kernel<true, true, false, false><<<dim3(24, 4), 64, 0, stream>>>(
            OBF, WT, T1, b_tp, nullptr, 200, 1536, 1536);
        gemm_kernel<false, true, true, true><<<dim3(24, 4), 64, 0, stream>>>(
            T1, WF, gdst, b_tf, gsrc, 200, 1536, 1536);
        float* tmp = gsrc; gsrc = gdst; gdst = tmp;
    }
    // 7) head
    head_kernel<<<8, 64, 0, stream>>>(gsrc, XR, w_head, b_head, (float*)d_out);
}

// Round 2
// 231.298 us; speedup vs baseline: 1.3890x; 1.3890x over previous
//
#include <hip/hip_runtime.h>

typedef __attribute__((ext_vector_type(8))) short short8;
typedef __attribute__((ext_vector_type(8))) unsigned short ushort8;
typedef __attribute__((ext_vector_type(4))) float f32x4;
typedef unsigned short ushort_t;

__device__ __forceinline__ ushort_t f2bf(float f) {
    unsigned u = __builtin_bit_cast(unsigned, f);
    u += 0x7fffu + ((u >> 16) & 1u);
    return (ushort_t)(u >> 16);
}
__device__ __forceinline__ float bf2f(ushort_t u) {
    unsigned v = ((unsigned)u) << 16;
    return __builtin_bit_cast(float, v);
}

__device__ __forceinline__ void load_lds16(const void* gp, void* lp) {
    __builtin_amdgcn_global_load_lds(
        (const __attribute__((address_space(1))) void*)gp,
        (__attribute__((address_space(3))) void*)lp, 16, 0, 0);
}

// ---------------------------------------------------------------------------
// prep kernel: block ranges do different jobs.
//   [0,7680)        pool: average 16x16 patch per (bt,c,i) -> AP bf16
//   [7680,14016)    cvt f32->bf16: w_qkv, w_tf, w_red, conv_w
//   [14016,14592)   transpose+cvt w_tp -> WTT bf16 (WTT[j][k] = w_tp[k][j])
//   [14592,14632)   cls-token init of GA rows
//   [14632,14728)   BC[i] = sum_k w_tf[i,k]*b_tp[k] + b_tf[i]
// ---------------------------------------------------------------------------
__global__ __launch_bounds__(256) void prep_kernel(
    const float* __restrict__ x, const float* __restrict__ w_qkv,
    const float* __restrict__ w_tf, const float* __restrict__ w_red,
    const float* __restrict__ conv_w, const float* __restrict__ w_tp,
    const float* __restrict__ b_tp, const float* __restrict__ b_tf,
    const float* __restrict__ cls,
    ushort_t* __restrict__ AP, ushort_t* __restrict__ WQ,
    ushort_t* __restrict__ WF, ushort_t* __restrict__ WR,
    ushort_t* __restrict__ WCV, ushort_t* __restrict__ WTT,
    float* __restrict__ BC, float* __restrict__ GA) {
    __shared__ __align__(16) float smem[64 * 68];
    int blk = blockIdx.x, tid = threadIdx.x;
    if (blk < 7680) {
        int bt = blk / 48, rc = blk % 48;
        int c = rc >> 4, i = rc & 15;
        int b = bt / 20, t = bt % 20;
        const float* base = x + (size_t)((b * 3 + c) * 20 + t) * 50176;
        int s = tid & 3;
        f32x4 acc = {0.f, 0.f, 0.f, 0.f};
        #pragma unroll
        for (int it = 0; it < 4; ++it) {
            int task = (tid >> 2) + (it << 6);
            if (task < 196) {
                int pi = task / 14, w4g = task % 14;
                acc += *(const f32x4*)(base + (16 * pi + i) * 224 + w4g * 16 + s * 4);
            }
        }
        f32x4* red = (f32x4*)smem;
        red[tid] = acc;
        __syncthreads();
        for (int str = 128; str >= 4; str >>= 1) {
            if (tid < str) red[tid] += red[tid + str];
            __syncthreads();
        }
        if (tid < 16) {
            float val = ((float*)red)[tid] * (1.0f / 196.0f);
            AP[(size_t)bt * 768 + c * 256 + i * 16 + tid] = f2bf(val);
        }
    } else if (blk < 14016) {
        long c = (long)(blk - 7680) * 256 + tid;
        const float* s; ushort_t* d; long i;
        if (c < 884736)       { s = w_qkv;  d = WQ;  i = c; }
        else if (c < 1179648) { s = w_tf;   d = WF;  i = c - 884736; }
        else if (c < 1474560) { s = w_red;  d = WR;  i = c - 1179648; }
        else                  { s = conv_w; d = WCV; i = c - 1474560; }
        i <<= 3;
        f32x4 a = *(const f32x4*)(s + i);
        f32x4 b = *(const f32x4*)(s + i + 4);
        ushort8 o;
        o[0] = f2bf(a[0]); o[1] = f2bf(a[1]); o[2] = f2bf(a[2]); o[3] = f2bf(a[3]);
        o[4] = f2bf(b[0]); o[5] = f2bf(b[1]); o[6] = f2bf(b[2]); o[7] = f2bf(b[3]);
        *(ushort8*)(d + i) = o;
    } else if (blk < 14592) {
        int tb = blk - 14016;
        int bi = tb / 24, bj = tb % 24;
        int r0 = (tid >> 4) << 2;
        int c0 = (tid & 15) << 2;
        #pragma unroll
        for (int rr = 0; rr < 4; ++rr) {
            f32x4 v = *(const f32x4*)(w_tp + (size_t)(bi * 64 + r0 + rr) * 1536 + bj * 64 + c0);
            smem[(r0 + rr) * 68 + c0 + 0] = v[0];
            smem[(r0 + rr) * 68 + c0 + 1] = v[1];
            smem[(r0 + rr) * 68 + c0 + 2] = v[2];
            smem[(r0 + rr) * 68 + c0 + 3] = v[3];
        }
        __syncthreads();
        #pragma unroll
        for (int rr = 0; rr < 4; ++rr) {
            int jj = r0 + rr;
            ushort4 o;
            o.x = f2bf(smem[(c0 + 0) * 68 + jj]);
            o.y = f2bf(smem[(c0 + 1) * 68 + jj]);
            o.z = f2bf(smem[(c0 + 2) * 68 + jj]);
            o.w = f2bf(smem[(c0 + 3) * 68 + jj]);
            *(ushort4*)(WTT + (size_t)(bj * 64 + jj) * 1536 + bi * 64 + c0) = o;
        }
    } else if (blk < 14632) {
        int cblk = blk - 14592;
        int b = cblk / 5, n = cblk % 5;
        size_t row = (size_t)(b * 25 + n * 5) * 1536;
        #pragma unroll
        for (int j = 0; j < 6; ++j) {
            int d = tid + j * 256;
            GA[row + d] = cls[n * 1536 + d];
        }
    } else {
        int bb = blk - 14632;
        int row = bb * 16 + (tid >> 4);
        int sub = tid & 15;
        float acc = 0.f;
        for (int j = 0; j < 96; ++j) {
            int k = sub + j * 16;
            acc += w_tf[(size_t)row * 1536 + k] * b_tp[k];
        }
        acc += __shfl_xor(acc, 1); acc += __shfl_xor(acc, 2);
        acc += __shfl_xor(acc, 4); acc += __shfl_xor(acc, 8);
        if (sub == 0) BC[row] = acc + b_tf[row];
    }
}

// ---------------------------------------------------------------------------
// bf16 MFMA GEMM: C[M,N] = A[M,K] @ B[N,K]^T (+bias)(+res); tile MT*16 x 64,
// single-wave WG, double-buffered LDS via global_load_lds, XOR-swizzled
// source + swizzled ds_read (conflict-free). Optional BUILD_G epilogue.
// ---------------------------------------------------------------------------
template <int MT, bool OUT_BF16, bool HAS_BIAS, bool HAS_RES, bool CLS_SWAP, bool BUILD_G>
__global__ __launch_bounds__(64) void gemm_kernel(
    const ushort_t* __restrict__ A, const ushort_t* __restrict__ B,
    void* __restrict__ Cv, const float* __restrict__ bias,
    const float* __restrict__ res, int M, int N, int K,
    float* __restrict__ g_out, const float* __restrict__ temb,
    const float* __restrict__ ts, const float* __restrict__ w_num,
    const float* __restrict__ b_num) {
    constexpr int BUFB = MT * 2048 + 8192;
    __shared__ __align__(16) char lds[2 * BUFB];
    const int lane = threadIdx.x;
    const int tn = blockIdx.x, tm = blockIdx.y;

    f32x4 acc[MT][4];
    #pragma unroll
    for (int m = 0; m < MT; ++m)
        #pragma unroll
        for (int n = 0; n < 4; ++n)
            acc[m][n] = (f32x4){0.f, 0.f, 0.f, 0.f};

    const int nK = K >> 6;
    const int rbase = lane >> 3, cc = lane & 7;

    auto stage = [&](int k0, int buf) {
        char* lA = lds + buf * BUFB;
        char* lB = lA + MT * 2048;
        #pragma unroll
        for (int j = 0; j < MT * 2; ++j) {
            int row = j * 8 + rbase;
            int cf = cc ^ (row & 7);
            int ga = tm * (MT * 16) + row; if (ga > M - 1) ga = M - 1;
            load_lds16(A + (size_t)ga * K + (k0 + cf * 8), lA + j * 1024);
        }
        #pragma unroll
        for (int j = 0; j < 8; ++j) {
            int row = j * 8 + rbase;
            int cf = cc ^ (row & 7);
            load_lds16(B + (size_t)(tn * 64 + row) * K + (k0 + cf * 8), lB + j * 1024);
        }
    };

    stage(0, 0);
    for (int t = 0; t < nK; ++t) {
        int cur = t & 1;
        if (t + 1 < nK) {
            stage((t + 1) << 6, cur ^ 1);
            if constexpr (MT == 2) asm volatile("s_waitcnt vmcnt(12)" ::: "memory");
            else                   asm volatile("s_waitcnt vmcnt(16)" ::: "memory");
        } else {
            asm volatile("s_waitcnt vmcnt(0)" ::: "memory");
        }
        __builtin_amdgcn_sched_barrier(0);
        const char* lA = lds + cur * BUFB;
        const char* lB = lA + MT * 2048;
        #pragma unroll
        for (int ks = 0; ks < 2; ++ks) {
            short8 av[MT], bv[4];
            const int rlo = lane & 15;
            const int chi = ks * 4 + (lane >> 4);
            #pragma unroll
            for (int m = 0; m < MT; ++m) {
                int r = m * 16 + rlo;
                av[m] = *(const short8*)(lA + r * 128 + ((chi ^ (r & 7)) << 4));
            }
            #pragma unroll
            for (int n = 0; n < 4; ++n) {
                int r = n * 16 + rlo;
                bv[n] = *(const short8*)(lB + r * 128 + ((chi ^ (r & 7)) << 4));
            }
            #pragma unroll
            for (int m = 0; m < MT; ++m)
                #pragma unroll
                for (int n = 0; n < 4; ++n)
                    acc[m][n] = __builtin_amdgcn_mfma_f32_16x16x32_bf16(
                        av[m], bv[n], acc[m][n], 0, 0, 0);
        }
    }

    const int c_l = lane & 15, r_q = (lane >> 4) * 4;
    #pragma unroll
    for (int m = 0; m < MT; ++m) {
        #pragma unroll
        for (int reg = 0; reg < 4; ++reg) {
            int r_ = tm * (MT * 16) + m * 16 + r_q + reg;
            if (r_ < M) {
                int r2 = r_;
                if (CLS_SWAP) {
                    int bb = r_ / 25, rem = r_ % 25;
                    if (rem % 5 == 0) r2 = bb * 25 + ((rem / 5 + 1) % 5) * 5;
                }
                #pragma unroll
                for (int n = 0; n < 4; ++n) {
                    int cc_ = tn * 64 + n * 16 + c_l;
                    float v = acc[m][n][reg];
                    if (HAS_BIAS) v += bias[cc_];
                    if (HAS_RES) v += res[(size_t)r_ * N + cc_];
                    if (OUT_BF16) ((ushort_t*)Cv)[(size_t)r2 * N + cc_] = f2bf(v);
                    else          ((float*)Cv)[(size_t)r2 * N + cc_] = v;
                    if (BUILD_G) {
                        int b = r_ / 20, t = r_ % 20;
                        float gval = v + temb[t * 1536 + cc_] +
                                     ts[b] * w_num[cc_] + b_num[cc_];
                        g_out[(size_t)(b * 25 + (t / 4) * 5 + (t % 4) + 1) * 1536 + cc_] = gval;
                    }
                }
            }
        }
    }
}

// ---------------------------------------------------------------------------
// LayerNorm over D=1536 -> bf16
// ---------------------------------------------------------------------------
__global__ __launch_bounds__(256) void ln_kernel(
    const float* __restrict__ g, const float* __restrict__ gamma,
    const float* __restrict__ beta, ushort_t* __restrict__ hn) {
    int r = blockIdx.x, tid = threadIdx.x;
    const float* x = g + (size_t)r * 1536;
    float v[6], s = 0.f, s2 = 0.f;
    #pragma unroll
    for (int j = 0; j < 6; ++j) {
        v[j] = x[tid + j * 256];
        s += v[j]; s2 += v[j] * v[j];
    }
    #pragma unroll
    for (int m = 1; m < 64; m <<= 1) { s += __shfl_xor(s, m); s2 += __shfl_xor(s2, m); }
    __shared__ float red[8];
    int wid = tid >> 6;
    if ((tid & 63) == 0) { red[wid] = s; red[4 + wid] = s2; }
    __syncthreads();
    s  = red[0] + red[1] + red[2] + red[3];
    s2 = red[4] + red[5] + red[6] + red[7];
    float mean = s * (1.0f / 1536.0f);
    float var  = s2 * (1.0f / 1536.0f) - mean * mean;
    float rstd = rsqrtf(var + 1e-5f);
    #pragma unroll
    for (int j = 0; j < 6; ++j) {
        int d = tid + j * 256;
        float y = (v[j] - mean) * rstd * gamma[d] + beta[d];
        hn[(size_t)r * 1536 + d] = f2bf(y);
    }
}

// ---------------------------------------------------------------------------
// Attention: one wave per (group, head). 5 tokens, hd=128 (2 dims/lane). bf16 io.
// ---------------------------------------------------------------------------
__global__ __launch_bounds__(64) void attn_kernel(const ushort_t* __restrict__ qkv,
                                                  ushort_t* __restrict__ o) {
    int gid = blockIdx.x;
    int h = gid % 12, gg = gid / 12;
    int l = threadIdx.x;
    const ushort_t* basep = qkv + (size_t)gg * 5 * 4608 + h * 128 + 2 * l;
    float q[5][2], k[5][2], v[5][2];
    #pragma unroll
    for (int tt = 0; tt < 5; ++tt) {
        ushort2 qv = *(const ushort2*)(basep + tt * 4608);
        ushort2 kv = *(const ushort2*)(basep + tt * 4608 + 1536);
        ushort2 vv = *(const ushort2*)(basep + tt * 4608 + 3072);
        q[tt][0] = bf2f(qv.x); q[tt][1] = bf2f(qv.y);
        k[tt][0] = bf2f(kv.x); k[tt][1] = bf2f(kv.y);
        v[tt][0] = bf2f(vv.x); v[tt][1] = bf2f(vv.y);
    }
    float sc[5][5];
    #pragma unroll
    for (int i = 0; i < 5; ++i)
        #pragma unroll
        for (int j = 0; j < 5; ++j)
            sc[i][j] = q[i][0] * k[j][0] + q[i][1] * k[j][1];
    #pragma unroll
    for (int m = 1; m < 64; m <<= 1)
        #pragma unroll
        for (int i = 0; i < 5; ++i)
            #pragma unroll
            for (int j = 0; j < 5; ++j)
                sc[i][j] += __shfl_xor(sc[i][j], m);
    const float scale = 0.08838834764831845f;
    float a_[5][5];
    #pragma unroll
    for (int i = 0; i < 5; ++i) {
        float mx = -1e30f;
        #pragma unroll
        for (int j = 0; j < 5; ++j) mx = fmaxf(mx, sc[i][j]);
        float sum = 0.f;
        #pragma unroll
        for (int j = 0; j < 5; ++j) { a_[i][j] = __expf((sc[i][j] - mx) * scale); sum += a_[i][j]; }
        float inv = 1.0f / sum;
        #pragma unroll
        for (int j = 0; j < 5; ++j) a_[i][j] *= inv;
    }
    #pragma unroll
    for (int i = 0; i < 5; ++i) {
        float o0 = 0.f, o1 = 0.f;
        #pragma unroll
        for (int j = 0; j < 5; ++j) { o0 += a_[i][j] * v[j][0]; o1 += a_[i][j] * v[j][1]; }
        ushort2 w; w.x = f2bf(o0); w.y = f2bf(o1);
        *(ushort2*)(o + (size_t)(gg * 5 + i) * 1536 + h * 128 + 2 * l) = w;
    }
}

// ---------------------------------------------------------------------------
// Head: out[b,c] = (g[b,4,4,:] + xr[b,19,:]) . w_head[c,:] + b_head[c]
// ---------------------------------------------------------------------------
__global__ __launch_bounds__(64) void head_kernel(
    const float* __restrict__ gfin, const float* __restrict__ xr,
    const float* __restrict__ w_head, const float* __restrict__ b_head,
    float* __restrict__ out) {
    int b = blockIdx.x, l = threadIdx.x;
    const float* gv = gfin + (size_t)(b * 25 + 24) * 1536;
    const float* xv = xr + (size_t)(b * 20 + 19) * 1536;
    float acc[7] = {0, 0, 0, 0, 0, 0, 0};
    for (int d = l; d < 1536; d += 64) {
        float xval = gv[d] + xv[d];
        #pragma unroll
        for (int c = 0; c < 7; ++c) acc[c] += xval * w_head[c * 1536 + d];
    }
    #pragma unroll
    for (int c = 0; c < 7; ++c)
        #pragma unroll
        for (int m = 1; m < 64; m <<= 1) acc[c] += __shfl_xor(acc[c], m);
    if (l == 0) {
        #pragma unroll
        for (int c = 0; c < 7; ++c) out[b * 7 + c] = acc[c] + b_head[c];
    }
}

// ---------------------------------------------------------------------------
// Workspace layout (bytes)
// ---------------------------------------------------------------------------
#define OFF_WQ   0u          // 14155776
#define OFF_WF   14155776u   // 4718592
#define OFF_WR   18874368u   // 4718592
#define OFF_WCV  23592960u   // 2359296
#define OFF_WTT  25952256u   // 4718592
#define OFF_WC   30670848u   // 4718592
#define OFF_BC   35389440u   // 6144
#define OFF_AP   35395584u   // 245760
#define OFF_FBF  35641344u   // 491520
#define OFF_XR   36132864u   // 983040
#define OFF_GA   37115904u   // 1228800
#define OFF_GB   38344704u   // 1228800
#define OFF_HN   39573504u   // 614400
#define OFF_QKV  40187904u   // 1843200
#define OFF_OBF  42031104u   // 614400

extern "C" void kernel_launch(void* const* d_in, const int* in_sizes, int n_in,
                              void* d_out, int out_size, void* d_ws, size_t ws_size,
                              hipStream_t stream) {
    const float* x      = (const float*)d_in[0];
    const float* ts     = (const float*)d_in[1];
    const float* conv_w = (const float*)d_in[2];
    const float* conv_b = (const float*)d_in[3];
    const float* w_red  = (const float*)d_in[4];
    const float* b_red  = (const float*)d_in[5];
    const float* w_num  = (const float*)d_in[6];
    const float* b_num  = (const float*)d_in[7];
    const float* temb   = (const float*)d_in[8];
    const float* cls    = (const float*)d_in[9];
    const float* ln_g   = (const float*)d_in[10];
    const float* ln_b   = (const float*)d_in[11];
    const float* w_qkv  = (const float*)d_in[12];
    const float* w_tp   = (const float*)d_in[13];
    const float* b_tp   = (const float*)d_in[14];
    const float* w_tf   = (const float*)d_in[15];
    const float* b_tf   = (const float*)d_in[16];
    const float* w_head = (const float*)d_in[17];
    const float* b_head = (const float*)d_in[18];

    char* ws = (char*)d_ws;
    ushort_t* WQ  = (ushort_t*)(ws + OFF_WQ);
    ushort_t* WF  = (ushort_t*)(ws + OFF_WF);
    ushort_t* WR  = (ushort_t*)(ws + OFF_WR);
    ushort_t* WCV = (ushort_t*)(ws + OFF_WCV);
    ushort_t* WTT = (ushort_t*)(ws + OFF_WTT);
    ushort_t* WC  = (ushort_t*)(ws + OFF_WC);
    float*    BC  = (float*)(ws + OFF_BC);
    ushort_t* AP  = (ushort_t*)(ws + OFF_AP);
    ushort_t* FBF = (ushort_t*)(ws + OFF_FBF);
    float*    XR  = (float*)(ws + OFF_XR);
    float*    GA  = (float*)(ws + OFF_GA);
    float*    GB  = (float*)(ws + OFF_GB);
    ushort_t* HN  = (ushort_t*)(ws + OFF_HN);
    ushort_t* QKV = (ushort_t*)(ws + OFF_QKV);
    ushort_t* OBF = (ushort_t*)(ws + OFF_OBF);

    // 1) prep: pool + cvt + transpose(w_tp) + cls init + combined bias
    prep_kernel<<<14728, 256, 0, stream>>>(x, w_qkv, w_tf, w_red, conv_w, w_tp,
                                           b_tp, b_tf, cls,
                                           AP, WQ, WF, WR, WCV, WTT, BC, GA);
    // 2) Wc = Wf @ Wt  (bf16): C[i,j] = sum_k WF[i,k] * WTT[j,k]
    gemm_kernel<4, true, false, false, false, false><<<dim3(24, 24), 64, 0, stream>>>(
        WF, WTT, WC, nullptr, nullptr, 1536, 1536, 1536,
        nullptr, nullptr, nullptr, nullptr, nullptr);
    // 3) f = ap @ conv_w^T + conv_b (bf16)
    gemm_kernel<2, true, true, false, false, false><<<dim3(24, 5), 64, 0, stream>>>(
        AP, WCV, FBF, conv_b, nullptr, 160, 1536, 768,
        nullptr, nullptr, nullptr, nullptr, nullptr);
    // 4) xr = f @ w_red^T + b_red (f32) + build g rows (k>0)
    gemm_kernel<2, false, true, false, false, true><<<dim3(24, 5), 64, 0, stream>>>(
        FBF, WR, XR, b_red, nullptr, 160, 1536, 1536,
        GA, temb, ts, w_num, b_num);

    float* gsrc = GA;
    float* gdst = GB;
    for (int it = 0; it < 4; ++it) {
        ln_kernel<<<200, 256, 0, stream>>>(gsrc, ln_g, ln_b, HN);
        gemm_kernel<4, true, false, false, false, false><<<dim3(72, 4), 64, 0, stream>>>(
            HN, WQ, QKV, nullptr, nullptr, 200, 4608, 1536,
            nullptr, nullptr, nullptr, nullptr, nullptr);
        attn_kernel<<<480, 64, 0, stream>>>(QKV, OBF);
        gemm_kernel<2, false, true, true, true, false><<<dim3(24, 7), 64, 0, stream>>>(
            OBF, WC, gdst, BC, gsrc, 200, 1536, 1536,
            nullptr, nullptr, nullptr, nullptr, nullptr);
        float* tmp = gsrc; gsrc = gdst; gdst = tmp;
    }
    head_kernel<<<8, 64, 0, stream>>>(gsrc, XR, w_head, b_head, (float*)d_out);
}

// Round 3
// 228.331 us; speedup vs baseline: 1.4070x; 1.0130x over previous
//
#include <hip/hip_runtime.h>

typedef __attribute__((ext_vector_type(8))) short short8;
typedef __attribute__((ext_vector_type(8))) unsigned short ushort8;
typedef __attribute__((ext_vector_type(4))) float f32x4;
typedef unsigned short ushort_t;

__device__ __forceinline__ ushort_t f2bf(float f) {
    unsigned u = __builtin_bit_cast(unsigned, f);
    u += 0x7fffu + ((u >> 16) & 1u);
    return (ushort_t)(u >> 16);
}
__device__ __forceinline__ float bf2f(ushort_t u) {
    unsigned v = ((unsigned)u) << 16;
    return __builtin_bit_cast(float, v);
}

__device__ __forceinline__ void load_lds16(const void* gp, void* lp) {
    __builtin_amdgcn_global_load_lds(
        (const __attribute__((address_space(1))) void*)gp,
        (__attribute__((address_space(3))) void*)lp, 16, 0, 0);
}

// ---------------------------------------------------------------------------
// prep kernel: block ranges do different jobs.
//   [0,1920)       pool: wave = (bt,c,i) row-class; lanes stream f32x4,
//                  shfl reduce, no LDS/barriers.
//   [1920,8256)    cvt f32->bf16: w_qkv, w_tf, w_red, conv_w
//   [8256,8832)    transpose+cvt w_tp -> WTT bf16 (WTT[j][k] = w_tp[k][j])
//   [8832,8872)    cls-token init of GA rows
//   [8872,8968)    BC[i] = sum_k w_tf[i,k]*b_tp[k] + b_tf[i]
// ---------------------------------------------------------------------------
__global__ __launch_bounds__(256) void prep_kernel(
    const float* __restrict__ x, const float* __restrict__ w_qkv,
    const float* __restrict__ w_tf, const float* __restrict__ w_red,
    const float* __restrict__ conv_w, const float* __restrict__ w_tp,
    const float* __restrict__ b_tp, const float* __restrict__ b_tf,
    const float* __restrict__ cls,
    ushort_t* __restrict__ AP, ushort_t* __restrict__ WQ,
    ushort_t* __restrict__ WF, ushort_t* __restrict__ WR,
    ushort_t* __restrict__ WCV, ushort_t* __restrict__ WTT,
    float* __restrict__ BC, float* __restrict__ GA) {
    __shared__ __align__(16) float smem[64 * 68];
    int blk = blockIdx.x, tid = threadIdx.x;
    if (blk < 1920) {
        // pool: 4 waves per block, wave w handles row class i = igrp*4+w
        int bt = blk / 12, rc = blk % 12;
        int c = rc >> 2, igrp = rc & 3;
        int w = tid >> 6, lane = tid & 63;
        int i = igrp * 4 + w;
        int b = bt / 20, t = bt % 20;
        const float* base = x + (size_t)((b * 3 + c) * 20 + t) * 50176;
        f32x4 acc = {0.f, 0.f, 0.f, 0.f};
        #pragma unroll
        for (int it = 0; it < 13; ++it) {
            int k = lane + it * 64;
            if (k < 784) {
                int ri = k / 56, c4 = k % 56;
                acc += *(const f32x4*)(base + (16 * ri + i) * 224 + 4 * c4);
            }
        }
        #pragma unroll
        for (int m = 4; m <= 32; m <<= 1) {
            acc[0] += __shfl_xor(acc[0], m);
            acc[1] += __shfl_xor(acc[1], m);
            acc[2] += __shfl_xor(acc[2], m);
            acc[3] += __shfl_xor(acc[3], m);
        }
        if (lane < 4) {
            ushort4 o;
            o.x = f2bf(acc[0] * (1.f / 196.f));
            o.y = f2bf(acc[1] * (1.f / 196.f));
            o.z = f2bf(acc[2] * (1.f / 196.f));
            o.w = f2bf(acc[3] * (1.f / 196.f));
            *(ushort4*)(AP + (size_t)bt * 768 + c * 256 + i * 16 + 4 * lane) = o;
        }
    } else if (blk < 8256) {
        long c = (long)(blk - 1920) * 256 + tid;
        const float* s; ushort_t* d; long i;
        if (c < 884736)       { s = w_qkv;  d = WQ;  i = c; }
        else if (c < 1179648) { s = w_tf;   d = WF;  i = c - 884736; }
        else if (c < 1474560) { s = w_red;  d = WR;  i = c - 1179648; }
        else                  { s = conv_w; d = WCV; i = c - 1474560; }
        i <<= 3;
        f32x4 a = *(const f32x4*)(s + i);
        f32x4 b = *(const f32x4*)(s + i + 4);
        ushort8 o;
        o[0] = f2bf(a[0]); o[1] = f2bf(a[1]); o[2] = f2bf(a[2]); o[3] = f2bf(a[3]);
        o[4] = f2bf(b[0]); o[5] = f2bf(b[1]); o[6] = f2bf(b[2]); o[7] = f2bf(b[3]);
        *(ushort8*)(d + i) = o;
    } else if (blk < 8832) {
        int tb = blk - 8256;
        int bi = tb / 24, bj = tb % 24;
        int r0 = (tid >> 4) << 2;
        int c0 = (tid & 15) << 2;
        #pragma unroll
        for (int rr = 0; rr < 4; ++rr) {
            f32x4 v = *(const f32x4*)(w_tp + (size_t)(bi * 64 + r0 + rr) * 1536 + bj * 64 + c0);
            smem[(r0 + rr) * 68 + c0 + 0] = v[0];
            smem[(r0 + rr) * 68 + c0 + 1] = v[1];
            smem[(r0 + rr) * 68 + c0 + 2] = v[2];
            smem[(r0 + rr) * 68 + c0 + 3] = v[3];
        }
        __syncthreads();
        #pragma unroll
        for (int rr = 0; rr < 4; ++rr) {
            int jj = r0 + rr;
            ushort4 o;
            o.x = f2bf(smem[(c0 + 0) * 68 + jj]);
            o.y = f2bf(smem[(c0 + 1) * 68 + jj]);
            o.z = f2bf(smem[(c0 + 2) * 68 + jj]);
            o.w = f2bf(smem[(c0 + 3) * 68 + jj]);
            *(ushort4*)(WTT + (size_t)(bj * 64 + jj) * 1536 + bi * 64 + c0) = o;
        }
    } else if (blk < 8872) {
        int cblk = blk - 8832;
        int b = cblk / 5, n = cblk % 5;
        size_t row = (size_t)(b * 25 + n * 5) * 1536;
        #pragma unroll
        for (int j = 0; j < 6; ++j) {
            int d = tid + j * 256;
            GA[row + d] = cls[n * 1536 + d];
        }
    } else {
        int bb = blk - 8872;
        int row = bb * 16 + (tid >> 4);
        int sub = tid & 15;
        float acc = 0.f;
        for (int j = 0; j < 96; ++j) {
            int k = sub + j * 16;
            acc += w_tf[(size_t)row * 1536 + k] * b_tp[k];
        }
        acc += __shfl_xor(acc, 1); acc += __shfl_xor(acc, 2);
        acc += __shfl_xor(acc, 4); acc += __shfl_xor(acc, 8);
        if (sub == 0) BC[row] = acc + b_tf[row];
    }
}

// ---------------------------------------------------------------------------
// bf16 MFMA GEMM: C[M,N] = A[M,K] @ B[N,K]^T (+bias)(+res); tile MT*16 x 64,
// single-wave WG, double-buffered LDS via global_load_lds, XOR-swizzled
// source + swizzled ds_read (conflict-free). Optional BUILD_G epilogue.
// ---------------------------------------------------------------------------
template <int MT, bool OUT_BF16, bool HAS_BIAS, bool HAS_RES, bool CLS_SWAP, bool BUILD_G>
__global__ __launch_bounds__(64) void gemm_kernel(
    const ushort_t* __restrict__ A, const ushort_t* __restrict__ B,
    void* __restrict__ Cv, const float* __restrict__ bias,
    const float* __restrict__ res, int M, int N, int K,
    float* __restrict__ g_out, const float* __restrict__ temb,
    const float* __restrict__ ts, const float* __restrict__ w_num,
    const float* __restrict__ b_num) {
    constexpr int BUFB = MT * 2048 + 8192;
    __shared__ __align__(16) char lds[2 * BUFB];
    const int lane = threadIdx.x;
    const int tn = blockIdx.x, tm = blockIdx.y;

    f32x4 acc[MT][4];
    #pragma unroll
    for (int m = 0; m < MT; ++m)
        #pragma unroll
        for (int n = 0; n < 4; ++n)
            acc[m][n] = (f32x4){0.f, 0.f, 0.f, 0.f};

    const int nK = K >> 6;
    const int rbase = lane >> 3, cc = lane & 7;

    auto stage = [&](int k0, int buf) {
        char* lA = lds + buf * BUFB;
        char* lB = lA + MT * 2048;
        #pragma unroll
        for (int j = 0; j < MT * 2; ++j) {
            int row = j * 8 + rbase;
            int cf = cc ^ (row & 7);
            int ga = tm * (MT * 16) + row; if (ga > M - 1) ga = M - 1;
            load_lds16(A + (size_t)ga * K + (k0 + cf * 8), lA + j * 1024);
        }
        #pragma unroll
        for (int j = 0; j < 8; ++j) {
            int row = j * 8 + rbase;
            int cf = cc ^ (row & 7);
            load_lds16(B + (size_t)(tn * 64 + row) * K + (k0 + cf * 8), lB + j * 1024);
        }
    };

    stage(0, 0);
    for (int t = 0; t < nK; ++t) {
        int cur = t & 1;
        if (t + 1 < nK) {
            stage((t + 1) << 6, cur ^ 1);
            if constexpr (MT == 2) asm volatile("s_waitcnt vmcnt(12)" ::: "memory");
            else                   asm volatile("s_waitcnt vmcnt(16)" ::: "memory");
        } else {
            asm volatile("s_waitcnt vmcnt(0)" ::: "memory");
        }
        __builtin_amdgcn_sched_barrier(0);
        const char* lA = lds + cur * BUFB;
        const char* lB = lA + MT * 2048;
        #pragma unroll
        for (int ks = 0; ks < 2; ++ks) {
            short8 av[MT], bv[4];
            const int rlo = lane & 15;
            const int chi = ks * 4 + (lane >> 4);
            #pragma unroll
            for (int m = 0; m < MT; ++m) {
                int r = m * 16 + rlo;
                av[m] = *(const short8*)(lA + r * 128 + ((chi ^ (r & 7)) << 4));
            }
            #pragma unroll
            for (int n = 0; n < 4; ++n) {
                int r = n * 16 + rlo;
                bv[n] = *(const short8*)(lB + r * 128 + ((chi ^ (r & 7)) << 4));
            }
            #pragma unroll
            for (int m = 0; m < MT; ++m)
                #pragma unroll
                for (int n = 0; n < 4; ++n)
                    acc[m][n] = __builtin_amdgcn_mfma_f32_16x16x32_bf16(
                        av[m], bv[n], acc[m][n], 0, 0, 0);
        }
    }

    const int c_l = lane & 15, r_q = (lane >> 4) * 4;
    #pragma unroll
    for (int m = 0; m < MT; ++m) {
        #pragma unroll
        for (int reg = 0; reg < 4; ++reg) {
            int r_ = tm * (MT * 16) + m * 16 + r_q + reg;
            if (r_ < M) {
                int r2 = r_;
                if (CLS_SWAP) {
                    int bb = r_ / 25, rem = r_ % 25;
                    if (rem % 5 == 0) r2 = bb * 25 + ((rem / 5 + 1) % 5) * 5;
                }
                #pragma unroll
                for (int n = 0; n < 4; ++n) {
                    int cc_ = tn * 64 + n * 16 + c_l;
                    float v = acc[m][n][reg];
                    if (HAS_BIAS) v += bias[cc_];
                    if (HAS_RES) v += res[(size_t)r_ * N + cc_];
                    if (OUT_BF16) ((ushort_t*)Cv)[(size_t)r2 * N + cc_] = f2bf(v);
                    else          ((float*)Cv)[(size_t)r2 * N + cc_] = v;
                    if (BUILD_G) {
                        int b = r_ / 20, t = r_ % 20;
                        float gval = v + temb[t * 1536 + cc_] +
                                     ts[b] * w_num[cc_] + b_num[cc_];
                        g_out[(size_t)(b * 25 + (t / 4) * 5 + (t % 4) + 1) * 1536 + cc_] = gval;
                    }
                }
            }
        }
    }
}

// ---------------------------------------------------------------------------
// LayerNorm over D=1536 -> bf16
// ---------------------------------------------------------------------------
__global__ __launch_bounds__(256) void ln_kernel(
    const float* __restrict__ g, const float* __restrict__ gamma,
    const float* __restrict__ beta, ushort_t* __restrict__ hn) {
    int r = blockIdx.x, tid = threadIdx.x;
    const float* x = g + (size_t)r * 1536;
    float v[6], s = 0.f, s2 = 0.f;
    #pragma unroll
    for (int j = 0; j < 6; ++j) {
        v[j] = x[tid + j * 256];
        s += v[j]; s2 += v[j] * v[j];
    }
    #pragma unroll
    for (int m = 1; m < 64; m <<= 1) { s += __shfl_xor(s, m); s2 += __shfl_xor(s2, m); }
    __shared__ float red[8];
    int wid = tid >> 6;
    if ((tid & 63) == 0) { red[wid] = s; red[4 + wid] = s2; }
    __syncthreads();
    s  = red[0] + red[1] + red[2] + red[3];
    s2 = red[4] + red[5] + red[6] + red[7];
    float mean = s * (1.0f / 1536.0f);
    float var  = s2 * (1.0f / 1536.0f) - mean * mean;
    float rstd = rsqrtf(var + 1e-5f);
    #pragma unroll
    for (int j = 0; j < 6; ++j) {
        int d = tid + j * 256;
        float y = (v[j] - mean) * rstd * gamma[d] + beta[d];
        hn[(size_t)r * 1536 + d] = f2bf(y);
    }
}

// ---------------------------------------------------------------------------
// Attention: one wave per (group, head). 5 tokens, hd=128 (2 dims/lane). bf16 io.
// ---------------------------------------------------------------------------
__global__ __launch_bounds__(64) void attn_kernel(const ushort_t* __restrict__ qkv,
                                                  ushort_t* __restrict__ o) {
    int gid = blockIdx.x;
    int h = gid % 12, gg = gid / 12;
    int l = threadIdx.x;
    const ushort_t* basep = qkv + (size_t)gg * 5 * 4608 + h * 128 + 2 * l;
    float q[5][2], k[5][2], v[5][2];
    #pragma unroll
    for (int tt = 0; tt < 5; ++tt) {
        ushort2 qv = *(const ushort2*)(basep + tt * 4608);
        ushort2 kv = *(const ushort2*)(basep + tt * 4608 + 1536);
        ushort2 vv = *(const ushort2*)(basep + tt * 4608 + 3072);
        q[tt][0] = bf2f(qv.x); q[tt][1] = bf2f(qv.y);
        k[tt][0] = bf2f(kv.x); k[tt][1] = bf2f(kv.y);
        v[tt][0] = bf2f(vv.x); v[tt][1] = bf2f(vv.y);
    }
    float sc[5][5];
    #pragma unroll
    for (int i = 0; i < 5; ++i)
        #pragma unroll
        for (int j = 0; j < 5; ++j)
            sc[i][j] = q[i][0] * k[j][0] + q[i][1] * k[j][1];
    #pragma unroll
    for (int m = 1; m < 64; m <<= 1)
        #pragma unroll
        for (int i = 0; i < 5; ++i)
            #pragma unroll
            for (int j = 0; j < 5; ++j)
                sc[i][j] += __shfl_xor(sc[i][j], m);
    const float scale = 0.08838834764831845f;
    float a_[5][5];
    #pragma unroll
    for (int i = 0; i < 5; ++i) {
        float mx = -1e30f;
        #pragma unroll
        for (int j = 0; j < 5; ++j) mx = fmaxf(mx, sc[i][j]);
        float sum = 0.f;
        #pragma unroll
        for (int j = 0; j < 5; ++j) { a_[i][j] = __expf((sc[i][j] - mx) * scale); sum += a_[i][j]; }
        float inv = 1.0f / sum;
        #pragma unroll
        for (int j = 0; j < 5; ++j) a_[i][j] *= inv;
    }
    #pragma unroll
    for (int i = 0; i < 5; ++i) {
        float o0 = 0.f, o1 = 0.f;
        #pragma unroll
        for (int j = 0; j < 5; ++j) { o0 += a_[i][j] * v[j][0]; o1 += a_[i][j] * v[j][1]; }
        ushort2 w; w.x = f2bf(o0); w.y = f2bf(o1);
        *(ushort2*)(o + (size_t)(gg * 5 + i) * 1536 + h * 128 + 2 * l) = w;
    }
}

// ---------------------------------------------------------------------------
// Head: out[b,c] = (g[b,4,4,:] + xr[b,19,:]) . w_head[c,:] + b_head[c]
// ---------------------------------------------------------------------------
__global__ __launch_bounds__(64) void head_kernel(
    const float* __restrict__ gfin, const float* __restrict__ xr,
    const float* __restrict__ w_head, const float* __restrict__ b_head,
    float* __restrict__ out) {
    int b = blockIdx.x, l = threadIdx.x;
    const float* gv = gfin + (size_t)(b * 25 + 24) * 1536;
    const float* xv = xr + (size_t)(b * 20 + 19) * 1536;
    float acc[7] = {0, 0, 0, 0, 0, 0, 0};
    for (int d = l; d < 1536; d += 64) {
        float xval = gv[d] + xv[d];
        #pragma unroll
        for (int c = 0; c < 7; ++c) acc[c] += xval * w_head[c * 1536 + d];
    }
    #pragma unroll
    for (int c = 0; c < 7; ++c)
        #pragma unroll
        for (int m = 1; m < 64; m <<= 1) acc[c] += __shfl_xor(acc[c], m);
    if (l == 0) {
        #pragma unroll
        for (int c = 0; c < 7; ++c) out[b * 7 + c] = acc[c] + b_head[c];
    }
}

// ---------------------------------------------------------------------------
// Workspace layout (bytes)
// ---------------------------------------------------------------------------
#define OFF_WQ   0u          // 14155776
#define OFF_WF   14155776u   // 4718592
#define OFF_WR   18874368u   // 4718592
#define OFF_WCV  23592960u   // 2359296
#define OFF_WTT  25952256u   // 4718592
#define OFF_WC   30670848u   // 4718592
#define OFF_BC   35389440u   // 6144
#define OFF_AP   35395584u   // 245760
#define OFF_FBF  35641344u   // 491520
#define OFF_XR   36132864u   // 983040
#define OFF_GA   37115904u   // 1228800
#define OFF_GB   38344704u   // 1228800
#define OFF_HN   39573504u   // 614400
#define OFF_QKV  40187904u   // 1843200
#define OFF_OBF  42031104u   // 614400

extern "C" void kernel_launch(void* const* d_in, const int* in_sizes, int n_in,
                              void* d_out, int out_size, void* d_ws, size_t ws_size,
                              hipStream_t stream) {
    const float* x      = (const float*)d_in[0];
    const float* ts     = (const float*)d_in[1];
    const float* conv_w = (const float*)d_in[2];
    const float* conv_b = (const float*)d_in[3];
    const float* w_red  = (const float*)d_in[4];
    const float* b_red  = (const float*)d_in[5];
    const float* w_num  = (const float*)d_in[6];
    const float* b_num  = (const float*)d_in[7];
    const float* temb   = (const float*)d_in[8];
    const float* cls    = (const float*)d_in[9];
    const float* ln_g   = (const float*)d_in[10];
    const float* ln_b   = (const float*)d_in[11];
    const float* w_qkv  = (const float*)d_in[12];
    const float* w_tp   = (const float*)d_in[13];
    const float* b_tp   = (const float*)d_in[14];
    const float* w_tf   = (const float*)d_in[15];
    const float* b_tf   = (const float*)d_in[16];
    const float* w_head = (const float*)d_in[17];
    const float* b_head = (const float*)d_in[18];

    char* ws = (char*)d_ws;
    ushort_t* WQ  = (ushort_t*)(ws + OFF_WQ);
    ushort_t* WF  = (ushort_t*)(ws + OFF_WF);
    ushort_t* WR  = (ushort_t*)(ws + OFF_WR);
    ushort_t* WCV = (ushort_t*)(ws + OFF_WCV);
    ushort_t* WTT = (ushort_t*)(ws + OFF_WTT);
    ushort_t* WC  = (ushort_t*)(ws + OFF_WC);
    float*    BC  = (float*)(ws + OFF_BC);
    ushort_t* AP  = (ushort_t*)(ws + OFF_AP);
    ushort_t* FBF = (ushort_t*)(ws + OFF_FBF);
    float*    XR  = (float*)(ws + OFF_XR);
    float*    GA  = (float*)(ws + OFF_GA);
    float*    GB  = (float*)(ws + OFF_GB);
    ushort_t* HN  = (ushort_t*)(ws + OFF_HN);
    ushort_t* QKV = (ushort_t*)(ws + OFF_QKV);
    ushort_t* OBF = (ushort_t*)(ws + OFF_OBF);

    // 1) prep: pool + cvt + transpose(w_tp) + cls init + combined bias
    prep_kernel<<<8968, 256, 0, stream>>>(x, w_qkv, w_tf, w_red, conv_w, w_tp,
                                          b_tp, b_tf, cls,
                                          AP, WQ, WF, WR, WCV, WTT, BC, GA);
    // 2) Wc = Wf @ Wt  (bf16): C[i,j] = sum_k WF[i,k] * WTT[j,k]
    gemm_kernel<4, true, false, false, false, false><<<dim3(24, 24), 64, 0, stream>>>(
        WF, WTT, WC, nullptr, nullptr, 1536, 1536, 1536,
        nullptr, nullptr, nullptr, nullptr, nullptr);
    // 3) f = ap @ conv_w^T + conv_b (bf16)
    gemm_kernel<2, true, true, false, false, false><<<dim3(24, 5), 64, 0, stream>>>(
        AP, WCV, FBF, conv_b, nullptr, 160, 1536, 768,
        nullptr, nullptr, nullptr, nullptr, nullptr);
    // 4) xr = f @ w_red^T + b_red (f32) + build g rows (k>0)
    gemm_kernel<2, false, true, false, false, true><<<dim3(24, 5), 64, 0, stream>>>(
        FBF, WR, XR, b_red, nullptr, 160, 1536, 1536,
        GA, temb, ts, w_num, b_num);

    float* gsrc = GA;
    float* gdst = GB;
    for (int it = 0; it < 4; ++it) {
        ln_kernel<<<200, 256, 0, stream>>>(gsrc, ln_g, ln_b, HN);
        gemm_kernel<4, true, false, false, false, false><<<dim3(72, 4), 64, 0, stream>>>(
            HN, WQ, QKV, nullptr, nullptr, 200, 4608, 1536,
            nullptr, nullptr, nullptr, nullptr, nullptr);
        attn_kernel<<<480, 64, 0, stream>>>(QKV, OBF);
        gemm_kernel<2, false, true, true, true, false><<<dim3(24, 7), 64, 0, stream>>>(
            OBF, WC, gdst, BC, gsrc, 200, 1536, 1536,
            nullptr, nullptr, nullptr, nullptr, nullptr);
        float* tmp = gsrc; gsrc = gdst; gdst = tmp;
    }
    head_kernel<<<8, 64, 0, stream>>>(gsrc, XR, w_head, b_head, (float*)d_out);
}